// Round 1
// baseline (699.516 us; speedup 1.0000x reference)
//
#include <hip/hip_runtime.h>
#include <stdint.h>

// ---- types ----
typedef short s16x8 __attribute__((ext_vector_type(8)));
typedef float f32x4 __attribute__((ext_vector_type(4)));
typedef unsigned int u32x4 __attribute__((ext_vector_type(4)));

// log2(e) / sqrt(128): fold softmax scale + exp2 conversion into Q projection
#define QSCALE 0.12751743f

__device__ __forceinline__ unsigned short f2bf(float f) {
  unsigned int u = __builtin_bit_cast(unsigned int, f);
  u += 0x7fffu + ((u >> 16) & 1u);   // RNE
  return (unsigned short)(u >> 16);
}

__device__ __forceinline__ f32x4 mfma16(s16x8 a, s16x8 b, f32x4 c) {
  return __builtin_amdgcn_mfma_f32_16x16x32_bf16(a, b, c, 0, 0, 0);
}

// ============ kernel 1: convert weights fp32 -> bf16 (Wq scaled) ============
__global__ __launch_bounds__(256) void wconv_k(const float* __restrict__ Wq,
                                               const float* __restrict__ Wk,
                                               const float* __restrict__ Wv,
                                               unsigned short* __restrict__ Wb) {
  int idx = (blockIdx.x * 256 + threadIdx.x) * 4;   // 3*128*1024 = 393216 elems
  int tensor = idx >> 17;                            // /131072
  int r = idx & 131071;
  const float* src = tensor == 0 ? Wq : (tensor == 1 ? Wk : Wv);
  float4 f = *(const float4*)(src + r);
  float sc = (tensor == 0) ? QSCALE : 1.0f;
  ushort4 o;
  o.x = f2bf(f.x * sc); o.y = f2bf(f.y * sc);
  o.z = f2bf(f.z * sc); o.w = f2bf(f.w * sc);
  *(ushort4*)(Wb + idx) = o;
}

// ============ kernel 2: QKV projection GEMM (M=16384, N=384, K=1024) ========
// block: 64 rows x all 384 cols, 256 threads (4 waves). wave w owns n-tiles
// w*6..w*6+5 over all 64 rows (4 m-tiles). BK=64. LDS strides padded to 72
// elems (144B = 9x16B granules: 16B-aligned b128 reads, 2-way banks = free).
__global__ __launch_bounds__(256) void proj_k(const float* __restrict__ x,
    const float* __restrict__ bq, const float* __restrict__ bk,
    const float* __restrict__ bv, const unsigned short* __restrict__ Wb,
    unsigned short* __restrict__ Qg, unsigned short* __restrict__ Kg,
    unsigned short* __restrict__ Vtg) {
  __shared__ unsigned short xs[64 * 72];     //  9.2 KB
  __shared__ unsigned short wsh[384 * 72];   // 55.3 KB (reused as Vt tile in epilogue)
  const int tid = threadIdx.x;
  const int wv = tid >> 6, ln = tid & 15, quad = (tid >> 4) & 3;
  const int mt = blockIdx.x;

  float bias[6];
  int tensor_[6], hcol_[6];
#pragma unroll
  for (int nt = 0; nt < 6; nt++) {
    int g_nt = wv * 6 + nt;
    int tensor = g_nt >> 3;
    int hcol = ((g_nt & 7) << 4) + ln;
    tensor_[nt] = tensor; hcol_[nt] = hcol;
    bias[nt] = (tensor == 0) ? bq[hcol] * QSCALE : (tensor == 1 ? bk[hcol] : bv[hcol]);
  }

  f32x4 acc[4][6];
  f32x4 zero = {0.f, 0.f, 0.f, 0.f};
#pragma unroll
  for (int m = 0; m < 4; m++)
#pragma unroll
    for (int nt = 0; nt < 6; nt++) acc[m][nt] = zero;

  for (int kc = 0; kc < 16; kc++) {
    // stage x chunk [64][64] fp32 -> bf16 LDS (512 granules)
    for (int g = tid; g < 512; g += 256) {
      int row = g >> 3, gc = g & 7;
      const float* p = x + (size_t)(mt * 64 + row) * 1024 + kc * 64 + gc * 8;
      float4 f0 = *(const float4*)p;
      float4 f1 = *(const float4*)(p + 4);
      u32x4 u;
      u.x = f2bf(f0.x) | ((unsigned)f2bf(f0.y) << 16);
      u.y = f2bf(f0.z) | ((unsigned)f2bf(f0.w) << 16);
      u.z = f2bf(f1.x) | ((unsigned)f2bf(f1.y) << 16);
      u.w = f2bf(f1.z) | ((unsigned)f2bf(f1.w) << 16);
      *(u32x4*)&xs[row * 72 + gc * 8] = u;
    }
    // stage W chunk [384][64] bf16 (384*9 = 3456 granules, 1 pad granule/row)
    for (int g = tid; g < 3456; g += 256) {
      int row = g / 9, gc = g - row * 9;
      if (gc < 8) {
        u32x4 u = *(const u32x4*)(Wb + (size_t)row * 1024 + kc * 64 + gc * 8);
        *(u32x4*)&wsh[row * 72 + gc * 8] = u;
      }
    }
    __syncthreads();
#pragma unroll
    for (int ks = 0; ks < 2; ks++) {
      s16x8 a[4];
#pragma unroll
      for (int m = 0; m < 4; m++)
        a[m] = __builtin_bit_cast(s16x8,
            *(const u32x4*)&xs[(m * 16 + ln) * 72 + ks * 32 + quad * 8]);
#pragma unroll
      for (int nt = 0; nt < 6; nt++) {
        s16x8 b = __builtin_bit_cast(s16x8,
            *(const u32x4*)&wsh[((wv * 6 + nt) * 16 + ln) * 72 + ks * 32 + quad * 8]);
#pragma unroll
        for (int m = 0; m < 4; m++)
          acc[m][nt] = mfma16(a[m], b, acc[m][nt]);
      }
    }
    __syncthreads();
  }

  // epilogue: C-layout row = quad*4+reg, col = ln (m89-verified)
  const int r0 = mt * 64;
  const int batch = r0 >> 12, t0 = r0 & 4095;
  unsigned short* vt = wsh;  // reuse as Vt tile [128][72]
#pragma unroll
  for (int nt = 0; nt < 6; nt++) {
#pragma unroll
    for (int m = 0; m < 4; m++) {
#pragma unroll
      for (int reg = 0; reg < 4; reg++) {
        float val = acc[m][nt][reg] + bias[nt];
        unsigned short h = f2bf(val);
        int rl = m * 16 + quad * 4 + reg;
        if (tensor_[nt] == 0)      Qg[(size_t)(r0 + rl) * 128 + hcol_[nt]] = h;
        else if (tensor_[nt] == 1) Kg[(size_t)(r0 + rl) * 128 + hcol_[nt]] = h;
        else                       vt[hcol_[nt] * 72 + rl] = h;   // transpose in LDS
      }
    }
  }
  __syncthreads();
  // coalesced copy-out of Vt tile: [128 h][64 t] -> Vtg[b][h][t]
  for (int g = tid; g < 1024; g += 256) {
    int h = g >> 3, gc = g & 7;
    u32x4 u = *(const u32x4*)&vt[h * 72 + gc * 8];
    *(u32x4*)((char*)Vtg + (size_t)batch * 1048576 + (size_t)h * 8192 + t0 * 2 + gc * 16) = u;
  }
}

// ============ kernel 3: causal flash attention ============
// BM=32 (2 waves, 16 q-rows each, Q in regs), BN=64. 512 blocks with causal
// work-pairing: blocks [0,256) get qtile p, [256,512) get 127-p.
__global__ __launch_bounds__(128) void attn_k(const unsigned short* __restrict__ Qg,
    const unsigned short* __restrict__ Kg, const unsigned short* __restrict__ Vtg,
    float* __restrict__ out) {
  __shared__ unsigned short Kl[64 * 136];  // stride 136 elems = 272B = 17x16B
  __shared__ unsigned short Vl[128 * 72];  // Vt chunk [h][t], stride 72
  __shared__ unsigned short Pl[32 * 72];   // P round-trip (C-layout -> A-layout)
  const int tid = threadIdx.x;
  const int wv = tid >> 6, ln = tid & 15, quad = (tid >> 4) & 3;
  const int id = blockIdx.x;
  const int p2 = id & 255;
  const int batch = p2 >> 6, p = p2 & 63;
  const int qt = (id & 256) ? (127 - p) : p;
  const int qbase = qt * 32;

  // Q fragments for this wave's 16 rows: A-layout (m=ln, k=quad*8+j +32*ks)
  const int qrow = batch * 4096 + qbase + wv * 16 + ln;
  u32x4 qf[4];
#pragma unroll
  for (int ks = 0; ks < 4; ks++)
    qf[ks] = *(const u32x4*)((const char*)Qg + (size_t)qrow * 256 + ks * 64 + quad * 16);

  f32x4 o[8];
  f32x4 zero = {0.f, 0.f, 0.f, 0.f};
#pragma unroll
  for (int i = 0; i < 8; i++) o[i] = zero;
  float m_run[4] = {-1e30f, -1e30f, -1e30f, -1e30f};
  float l_run[4] = {0.f, 0.f, 0.f, 0.f};

  const int nchunks = (qt >> 1) + 1;
  for (int c = 0; c < nchunks; c++) {
    const int t0 = c * 64;
    // stage K chunk [64][128] bf16 (64*17 granules, 1 pad/row)
    for (int g = tid; g < 1088; g += 128) {
      int row = g / 17, gc = g - row * 17;
      if (gc < 16) {
        u32x4 u = *(const u32x4*)((const char*)Kg
                    + (size_t)(batch * 4096 + t0 + row) * 256 + gc * 16);
        *(u32x4*)&Kl[row * 136 + gc * 8] = u;
      }
    }
    // stage Vt chunk [128][64] (128*9 granules)
    for (int g = tid; g < 1152; g += 128) {
      int row = g / 9, gc = g - row * 9;
      if (gc < 8) {
        u32x4 u = *(const u32x4*)((const char*)Vtg + (size_t)batch * 1048576
                    + (size_t)row * 8192 + t0 * 2 + gc * 16);
        *(u32x4*)&Vl[row * 72 + gc * 8] = u;
      }
    }
    __syncthreads();

    // S = Q K^T (already in log2 domain via QSCALE folding)
    f32x4 s[4];
#pragma unroll
    for (int nt = 0; nt < 4; nt++) {
      s[nt] = zero;
#pragma unroll
      for (int ks = 0; ks < 4; ks++) {
        s16x8 b = __builtin_bit_cast(s16x8,
            *(const u32x4*)&Kl[(nt * 16 + ln) * 136 + ks * 32 + quad * 8]);
        s[nt] = mfma16(__builtin_bit_cast(s16x8, qf[ks]), b, s[nt]);
      }
    }
    // causal mask (only diagonal-touching chunks enter)
    if (t0 + 63 > qbase) {
#pragma unroll
      for (int nt = 0; nt < 4; nt++)
#pragma unroll
        for (int reg = 0; reg < 4; reg++) {
          int kidx = t0 + nt * 16 + ln;
          int qidx = qbase + wv * 16 + quad * 4 + reg;
          if (kidx > qidx) s[nt][reg] = -1e30f;
        }
    }
    // online softmax; rows owned per 16-lane group (row = quad*4+reg)
    float mx[4], al[4], rs[4];
#pragma unroll
    for (int reg = 0; reg < 4; reg++)
      mx[reg] = fmaxf(fmaxf(s[0][reg], s[1][reg]), fmaxf(s[2][reg], s[3][reg]));
#pragma unroll
    for (int off = 1; off < 16; off <<= 1)
#pragma unroll
      for (int reg = 0; reg < 4; reg++)
        mx[reg] = fmaxf(mx[reg], __shfl_xor(mx[reg], off, 64));
#pragma unroll
    for (int reg = 0; reg < 4; reg++) {
      float mn = fmaxf(m_run[reg], mx[reg]);
      al[reg] = exp2f(m_run[reg] - mn);
      m_run[reg] = mn;
      rs[reg] = 0.f;
    }
#pragma unroll
    for (int nt = 0; nt < 4; nt++)
#pragma unroll
      for (int reg = 0; reg < 4; reg++) {
        float pv = exp2f(s[nt][reg] - m_run[reg]);
        s[nt][reg] = pv;
        rs[reg] += pv;
      }
#pragma unroll
    for (int off = 1; off < 16; off <<= 1)
#pragma unroll
      for (int reg = 0; reg < 4; reg++)
        rs[reg] += __shfl_xor(rs[reg], off, 64);
#pragma unroll
    for (int reg = 0; reg < 4; reg++)
      l_run[reg] = l_run[reg] * al[reg] + rs[reg];
#pragma unroll
    for (int i = 0; i < 8; i++)
#pragma unroll
      for (int reg = 0; reg < 4; reg++)
        o[i][reg] *= al[reg];

    // P: C-layout -> LDS -> A-layout (wave-private rows, DS in-order per wave)
#pragma unroll
    for (int nt = 0; nt < 4; nt++)
#pragma unroll
      for (int reg = 0; reg < 4; reg++)
        Pl[(wv * 16 + quad * 4 + reg) * 72 + nt * 16 + ln] = f2bf(s[nt][reg]);

#pragma unroll
    for (int ks2 = 0; ks2 < 2; ks2++) {
      s16x8 pa = __builtin_bit_cast(s16x8,
          *(const u32x4*)&Pl[(wv * 16 + ln) * 72 + ks2 * 32 + quad * 8]);
#pragma unroll
      for (int nh = 0; nh < 8; nh++) {
        s16x8 vb = __builtin_bit_cast(s16x8,
            *(const u32x4*)&Vl[(nh * 16 + ln) * 72 + ks2 * 32 + quad * 8]);
        o[nh] = mfma16(pa, vb, o[nh]);
      }
    }
    __syncthreads();
  }

  // epilogue: divide by l, write fp32 out [b][t][128]
#pragma unroll
  for (int reg = 0; reg < 4; reg++) {
    float inv = 1.0f / l_run[reg];
    int row = batch * 4096 + qbase + wv * 16 + quad * 4 + reg;
#pragma unroll
    for (int nh = 0; nh < 8; nh++)
      out[(size_t)row * 128 + nh * 16 + ln] = o[nh][reg] * inv;
  }
}

// ============ launch ============
extern "C" void kernel_launch(void* const* d_in, const int* in_sizes, int n_in,
                              void* d_out, int out_size, void* d_ws, size_t ws_size,
                              hipStream_t stream) {
  const float* x  = (const float*)d_in[0];
  const float* Wq = (const float*)d_in[1];
  const float* bq = (const float*)d_in[2];
  const float* Wk = (const float*)d_in[3];
  const float* bk = (const float*)d_in[4];
  const float* Wv = (const float*)d_in[5];
  const float* bv = (const float*)d_in[6];
  float* out = (float*)d_out;

  char* wsb = (char*)d_ws;
  unsigned short* Wb  = (unsigned short*)wsb;                          // 786432 B
  unsigned short* Qg  = (unsigned short*)(wsb + 786432);               // 4 MB
  unsigned short* Kg  = (unsigned short*)(wsb + 786432 + 4194304);     // 4 MB
  unsigned short* Vtg = (unsigned short*)(wsb + 786432 + 2 * 4194304); // 4 MB

  wconv_k<<<dim3(384), dim3(256), 0, stream>>>(Wq, Wk, Wv, Wb);
  proj_k<<<dim3(256), dim3(256), 0, stream>>>(x, bq, bk, bv, Wb, Qg, Kg, Vtg);
  attn_k<<<dim3(512), dim3(128), 0, stream>>>(Qg, Kg, Vtg, out);
}

// Round 2
// 249.675 us; speedup vs baseline: 2.8017x; 2.8017x over previous
//
#include <hip/hip_runtime.h>
#include <stdint.h>

// ---- types ----
typedef short s16x8 __attribute__((ext_vector_type(8)));
typedef float f32x4 __attribute__((ext_vector_type(4)));
typedef unsigned int u32x4 __attribute__((ext_vector_type(4)));

// log2(e) / sqrt(128): fold softmax scale + exp2 conversion into Q projection
#define QSCALE 0.12751743f

__device__ __forceinline__ unsigned short f2bf(float f) {
  unsigned int u = __builtin_bit_cast(unsigned int, f);
  u += 0x7fffu + ((u >> 16) & 1u);   // RNE
  return (unsigned short)(u >> 16);
}

__device__ __forceinline__ f32x4 mfma16(s16x8 a, s16x8 b, f32x4 c) {
  return __builtin_amdgcn_mfma_f32_16x16x32_bf16(a, b, c, 0, 0, 0);
}

// ============ kernel 1: convert weights fp32 -> bf16 (Wq scaled) ============
__global__ __launch_bounds__(256) void wconv_k(const float* __restrict__ Wq,
                                               const float* __restrict__ Wk,
                                               const float* __restrict__ Wv,
                                               unsigned short* __restrict__ Wb) {
  int idx = (blockIdx.x * 256 + threadIdx.x) * 4;   // 3*128*1024 = 393216 elems
  int tensor = idx >> 17;                            // /131072
  int r = idx & 131071;
  const float* src = tensor == 0 ? Wq : (tensor == 1 ? Wk : Wv);
  float4 f = *(const float4*)(src + r);
  float sc = (tensor == 0) ? QSCALE : 1.0f;
  ushort4 o;
  o.x = f2bf(f.x * sc); o.y = f2bf(f.y * sc);
  o.z = f2bf(f.z * sc); o.w = f2bf(f.w * sc);
  *(ushort4*)(Wb + idx) = o;
}

// ============ kernel 2: QKV projection GEMM (M=16384, N=384, K=1024) ========
// 256 threads (4 waves); wave w owns n-tiles w*6..w*6+5 over 64 rows.
// Register-staged, double-buffered: all loads for kc+1 issue back-to-back and
// overlap the MFMAs of kc (fixes the serial load->wait->write latency chain).
__global__ __launch_bounds__(256, 2) void proj_k(const float* __restrict__ x,
    const float* __restrict__ bq, const float* __restrict__ bk,
    const float* __restrict__ bv, const unsigned short* __restrict__ Wb,
    unsigned short* __restrict__ Qg, unsigned short* __restrict__ Kg,
    unsigned short* __restrict__ Vtg) {
  __shared__ unsigned short xs[64 * 72];     //  9.2 KB
  __shared__ unsigned short wsh[384 * 72];   // 55.3 KB (reused as Vt tile)
  const int tid = threadIdx.x;
  const int wv = tid >> 6, ln = tid & 15, quad = (tid >> 4) & 3;
  const int mt = blockIdx.x;

  float bias[6];
  int tensor_[6], hcol_[6];
#pragma unroll
  for (int nt = 0; nt < 6; nt++) {
    int g_nt = wv * 6 + nt;
    int tensor = g_nt >> 3;
    int hcol = ((g_nt & 7) << 4) + ln;
    tensor_[nt] = tensor; hcol_[nt] = hcol;
    bias[nt] = (tensor == 0) ? bq[hcol] * QSCALE : (tensor == 1 ? bk[hcol] : bv[hcol]);
  }

  f32x4 acc[4][6];
  f32x4 zero = {0.f, 0.f, 0.f, 0.f};
#pragma unroll
  for (int m = 0; m < 4; m++)
#pragma unroll
    for (int nt = 0; nt < 6; nt++) acc[m][nt] = zero;

  // staging registers: 12 W granules (16B) + 2 x granules (as 4x float4)
  u32x4 rW[12];
  float4 rX[4];

#define LOAD_W(KC)                                                             \
  _Pragma("unroll") for (int k = 0; k < 12; k++) {                             \
    int g = k * 256 + tid; int row = g >> 3, gc = g & 7;                       \
    rW[k] = *(const u32x4*)(Wb + (size_t)row * 1024 + (KC) * 64 + gc * 8);     \
  }
#define LOAD_X(KC)                                                             \
  _Pragma("unroll") for (int k = 0; k < 2; k++) {                              \
    int g = k * 256 + tid; int row = g >> 3, gc = g & 7;                       \
    const float* p = x + (size_t)(mt * 64 + row) * 1024 + (KC) * 64 + gc * 8;  \
    rX[k * 2]     = *(const float4*)p;                                         \
    rX[k * 2 + 1] = *(const float4*)(p + 4);                                   \
  }
#define WRITE_STAGE()                                                          \
  _Pragma("unroll") for (int k = 0; k < 2; k++) {                              \
    int g = k * 256 + tid; int row = g >> 3, gc = g & 7;                       \
    float4 f0 = rX[k * 2], f1 = rX[k * 2 + 1];                                 \
    u32x4 u;                                                                   \
    u.x = f2bf(f0.x) | ((unsigned)f2bf(f0.y) << 16);                           \
    u.y = f2bf(f0.z) | ((unsigned)f2bf(f0.w) << 16);                           \
    u.z = f2bf(f1.x) | ((unsigned)f2bf(f1.y) << 16);                           \
    u.w = f2bf(f1.z) | ((unsigned)f2bf(f1.w) << 16);                           \
    *(u32x4*)&xs[row * 72 + gc * 8] = u;                                       \
  }                                                                            \
  _Pragma("unroll") for (int k = 0; k < 12; k++) {                             \
    int g = k * 256 + tid; int row = g >> 3, gc = g & 7;                       \
    *(u32x4*)&wsh[row * 72 + gc * 8] = rW[k];                                  \
  }

  LOAD_W(0); LOAD_X(0);
  for (int kc = 0; kc < 16; kc++) {
    WRITE_STAGE();
    __syncthreads();
    if (kc + 1 < 16) { LOAD_W(kc + 1); LOAD_X(kc + 1); }
#pragma unroll
    for (int ks = 0; ks < 2; ks++) {
      s16x8 a[4];
#pragma unroll
      for (int m = 0; m < 4; m++)
        a[m] = __builtin_bit_cast(s16x8,
            *(const u32x4*)&xs[(m * 16 + ln) * 72 + ks * 32 + quad * 8]);
#pragma unroll
      for (int nt = 0; nt < 6; nt++) {
        s16x8 b = __builtin_bit_cast(s16x8,
            *(const u32x4*)&wsh[((wv * 6 + nt) * 16 + ln) * 72 + ks * 32 + quad * 8]);
#pragma unroll
        for (int m = 0; m < 4; m++)
          acc[m][nt] = mfma16(a[m], b, acc[m][nt]);
      }
    }
    __syncthreads();
  }

  // epilogue: C-layout row = quad*4+reg, col = ln (m89-verified)
  const int r0 = mt * 64;
  const int batch = r0 >> 12, t0 = r0 & 4095;
  unsigned short* vt = wsh;  // reuse as Vt tile [128][72]
#pragma unroll
  for (int nt = 0; nt < 6; nt++) {
#pragma unroll
    for (int m = 0; m < 4; m++) {
#pragma unroll
      for (int reg = 0; reg < 4; reg++) {
        float val = acc[m][nt][reg] + bias[nt];
        unsigned short h = f2bf(val);
        int rl = m * 16 + quad * 4 + reg;
        if (tensor_[nt] == 0)      Qg[(size_t)(r0 + rl) * 128 + hcol_[nt]] = h;
        else if (tensor_[nt] == 1) Kg[(size_t)(r0 + rl) * 128 + hcol_[nt]] = h;
        else                       vt[hcol_[nt] * 72 + rl] = h;   // transpose in LDS
      }
    }
  }
  __syncthreads();
  // coalesced copy-out of Vt tile: [128 h][64 t] -> Vtg[b][h][t]
  for (int g = tid; g < 1024; g += 256) {
    int h = g >> 3, gc = g & 7;
    u32x4 u = *(const u32x4*)&vt[h * 72 + gc * 8];
    *(u32x4*)((char*)Vtg + (size_t)batch * 1048576 + (size_t)h * 8192 + t0 * 2 + gc * 16) = u;
  }
}

// ============ kernel 3: causal flash attention ============
// BM=32 (2 waves x 16 q-rows, Q in regs), BN=64. 512 blocks, causal pairing.
// Register-staged double-buffer: 16 independent 16B loads for chunk c+1 issue
// before the chunk-c compute and complete during it (one latency exposure).
__global__ __launch_bounds__(128) void attn_k(const unsigned short* __restrict__ Qg,
    const unsigned short* __restrict__ Kg, const unsigned short* __restrict__ Vtg,
    float* __restrict__ out) {
  __shared__ unsigned short Kl[64 * 136];  // stride 136 elems: padded, 2-way banks
  __shared__ unsigned short Vl[128 * 72];  // Vt chunk [h][t], stride 72
  __shared__ unsigned short Pl[32 * 72];   // P round-trip (C-layout -> A-layout)
  const int tid = threadIdx.x;
  const int wv = tid >> 6, ln = tid & 15, quad = (tid >> 4) & 3;
  const int id = blockIdx.x;
  const int p2 = id & 255;
  const int batch = p2 >> 6, p = p2 & 63;
  const int qt = (id & 256) ? (127 - p) : p;
  const int qbase = qt * 32;

  const char* Kbase = (const char*)Kg + (size_t)batch * 1048576;  // [t][h] 256B rows
  const char* Vbase = (const char*)Vtg + (size_t)batch * 1048576; // [h][t] 8192B rows

  // Q fragments for this wave's 16 rows: A-layout (m=ln, k=quad*8+j +32*ks)
  const int qrow = batch * 4096 + qbase + wv * 16 + ln;
  u32x4 qf[4];
#pragma unroll
  for (int ks = 0; ks < 4; ks++)
    qf[ks] = *(const u32x4*)((const char*)Qg + (size_t)qrow * 256 + ks * 64 + quad * 16);

  f32x4 o[8];
  f32x4 zero = {0.f, 0.f, 0.f, 0.f};
#pragma unroll
  for (int i = 0; i < 8; i++) o[i] = zero;
  float m_run[4] = {-1e30f, -1e30f, -1e30f, -1e30f};
  float l_run[4] = {0.f, 0.f, 0.f, 0.f};

  u32x4 rK[8], rV[8];
#define LOAD_KV(T0)                                                            \
  _Pragma("unroll") for (int k = 0; k < 8; k++) {                              \
    int g = k * 128 + tid;                                                     \
    rK[k] = *(const u32x4*)(Kbase + (size_t)(T0) * 256 + (size_t)g * 16);      \
  }                                                                            \
  _Pragma("unroll") for (int k = 0; k < 8; k++) {                              \
    int g = k * 128 + tid; int row = g >> 3, gc = g & 7;                       \
    rV[k] = *(const u32x4*)(Vbase + (size_t)row * 8192 + (T0) * 2 + gc * 16);  \
  }
#define WRITE_KV()                                                             \
  _Pragma("unroll") for (int k = 0; k < 8; k++) {                              \
    int g = k * 128 + tid; int row = g >> 4, gc = g & 15;                      \
    *(u32x4*)&Kl[row * 136 + gc * 8] = rK[k];                                  \
  }                                                                            \
  _Pragma("unroll") for (int k = 0; k < 8; k++) {                              \
    int g = k * 128 + tid; int row = g >> 3, gc = g & 7;                       \
    *(u32x4*)&Vl[row * 72 + gc * 8] = rV[k];                                   \
  }

  const int nchunks = (qt >> 1) + 1;
  LOAD_KV(0);
  for (int c = 0; c < nchunks; c++) {
    const int t0 = c * 64;
    WRITE_KV();
    __syncthreads();
    if (c + 1 < nchunks) { LOAD_KV(t0 + 64); }

    // S = Q K^T (already in log2 domain via QSCALE folding)
    f32x4 s[4];
#pragma unroll
    for (int nt = 0; nt < 4; nt++) {
      s[nt] = zero;
#pragma unroll
      for (int ks = 0; ks < 4; ks++) {
        s16x8 b = __builtin_bit_cast(s16x8,
            *(const u32x4*)&Kl[(nt * 16 + ln) * 136 + ks * 32 + quad * 8]);
        s[nt] = mfma16(__builtin_bit_cast(s16x8, qf[ks]), b, s[nt]);
      }
    }
    // causal mask (only diagonal-touching chunks enter)
    if (t0 + 63 > qbase) {
#pragma unroll
      for (int nt = 0; nt < 4; nt++)
#pragma unroll
        for (int reg = 0; reg < 4; reg++) {
          int kidx = t0 + nt * 16 + ln;
          int qidx = qbase + wv * 16 + quad * 4 + reg;
          if (kidx > qidx) s[nt][reg] = -1e30f;
        }
    }
    // online softmax; rows owned per 16-lane group (row = quad*4+reg)
    float mx[4], al[4], rs[4];
#pragma unroll
    for (int reg = 0; reg < 4; reg++)
      mx[reg] = fmaxf(fmaxf(s[0][reg], s[1][reg]), fmaxf(s[2][reg], s[3][reg]));
#pragma unroll
    for (int off = 1; off < 16; off <<= 1)
#pragma unroll
      for (int reg = 0; reg < 4; reg++)
        mx[reg] = fmaxf(mx[reg], __shfl_xor(mx[reg], off, 64));
#pragma unroll
    for (int reg = 0; reg < 4; reg++) {
      float mn = fmaxf(m_run[reg], mx[reg]);
      al[reg] = __builtin_amdgcn_exp2f(m_run[reg] - mn);
      m_run[reg] = mn;
      rs[reg] = 0.f;
    }
#pragma unroll
    for (int nt = 0; nt < 4; nt++)
#pragma unroll
      for (int reg = 0; reg < 4; reg++) {
        float pv = __builtin_amdgcn_exp2f(s[nt][reg] - m_run[reg]);
        s[nt][reg] = pv;
        rs[reg] += pv;
      }
#pragma unroll
    for (int off = 1; off < 16; off <<= 1)
#pragma unroll
      for (int reg = 0; reg < 4; reg++)
        rs[reg] += __shfl_xor(rs[reg], off, 64);
#pragma unroll
    for (int reg = 0; reg < 4; reg++)
      l_run[reg] = l_run[reg] * al[reg] + rs[reg];
#pragma unroll
    for (int i = 0; i < 8; i++)
#pragma unroll
      for (int reg = 0; reg < 4; reg++)
        o[i][reg] *= al[reg];

    // P: C-layout -> LDS -> A-layout (wave-private rows)
#pragma unroll
    for (int nt = 0; nt < 4; nt++)
#pragma unroll
      for (int reg = 0; reg < 4; reg++)
        Pl[(wv * 16 + quad * 4 + reg) * 72 + nt * 16 + ln] = f2bf(s[nt][reg]);

#pragma unroll
    for (int ks2 = 0; ks2 < 2; ks2++) {
      s16x8 pa = __builtin_bit_cast(s16x8,
          *(const u32x4*)&Pl[(wv * 16 + ln) * 72 + ks2 * 32 + quad * 8]);
#pragma unroll
      for (int nh = 0; nh < 8; nh++) {
        s16x8 vb = __builtin_bit_cast(s16x8,
            *(const u32x4*)&Vl[(nh * 16 + ln) * 72 + ks2 * 32 + quad * 8]);
        o[nh] = mfma16(pa, vb, o[nh]);
      }
    }
    __syncthreads();
  }

  // epilogue: divide by l, write fp32 out [b][t][128]
#pragma unroll
  for (int reg = 0; reg < 4; reg++) {
    float inv = 1.0f / l_run[reg];
    int row = batch * 4096 + qbase + wv * 16 + quad * 4 + reg;
#pragma unroll
    for (int nh = 0; nh < 8; nh++)
      out[(size_t)row * 128 + nh * 16 + ln] = o[nh][reg] * inv;
  }
}

// ============ launch ============
extern "C" void kernel_launch(void* const* d_in, const int* in_sizes, int n_in,
                              void* d_out, int out_size, void* d_ws, size_t ws_size,
                              hipStream_t stream) {
  const float* x  = (const float*)d_in[0];
  const float* Wq = (const float*)d_in[1];
  const float* bq = (const float*)d_in[2];
  const float* Wk = (const float*)d_in[3];
  const float* bk = (const float*)d_in[4];
  const float* Wv = (const float*)d_in[5];
  const float* bv = (const float*)d_in[6];
  float* out = (float*)d_out;

  char* wsb = (char*)d_ws;
  unsigned short* Wb  = (unsigned short*)wsb;                          // 786432 B
  unsigned short* Qg  = (unsigned short*)(wsb + 786432);               // 4 MB
  unsigned short* Kg  = (unsigned short*)(wsb + 786432 + 4194304);     // 4 MB
  unsigned short* Vtg = (unsigned short*)(wsb + 786432 + 2 * 4194304); // 4 MB

  wconv_k<<<dim3(384), dim3(256), 0, stream>>>(Wq, Wk, Wv, Wb);
  proj_k<<<dim3(256), dim3(256), 0, stream>>>(x, bq, bk, bv, Wb, Qg, Kg, Vtg);
  attn_k<<<dim3(512), dim3(128), 0, stream>>>(Qg, Kg, Vtg, out);
}

// Round 3
// 232.475 us; speedup vs baseline: 3.0090x; 1.0740x over previous
//
#include <hip/hip_runtime.h>
#include <stdint.h>

// ---- types ----
typedef short s16x8 __attribute__((ext_vector_type(8)));
typedef float f32x4 __attribute__((ext_vector_type(4)));
typedef unsigned int u32x4 __attribute__((ext_vector_type(4)));

// log2(e) / sqrt(128): fold softmax scale + exp2 conversion into Q projection
#define QSCALE 0.12751743f

__device__ __forceinline__ unsigned short f2bf(float f) {
  unsigned int u = __builtin_bit_cast(unsigned int, f);
  u += 0x7fffu + ((u >> 16) & 1u);   // RNE
  return (unsigned short)(u >> 16);
}

__device__ __forceinline__ f32x4 mfma16(s16x8 a, s16x8 b, f32x4 c) {
  return __builtin_amdgcn_mfma_f32_16x16x32_bf16(a, b, c, 0, 0, 0);
}

// ============ kernel 1: convert weights fp32 -> bf16 (Wq scaled) ============
__global__ __launch_bounds__(256) void wconv_k(const float* __restrict__ Wq,
                                               const float* __restrict__ Wk,
                                               const float* __restrict__ Wv,
                                               unsigned short* __restrict__ Wb) {
  int idx = (blockIdx.x * 256 + threadIdx.x) * 4;   // 3*128*1024 = 393216 elems
  int tensor = idx >> 17;                            // /131072
  int r = idx & 131071;
  const float* src = tensor == 0 ? Wq : (tensor == 1 ? Wk : Wv);
  float4 f = *(const float4*)(src + r);
  float sc = (tensor == 0) ? QSCALE : 1.0f;
  ushort4 o;
  o.x = f2bf(f.x * sc); o.y = f2bf(f.y * sc);
  o.z = f2bf(f.z * sc); o.w = f2bf(f.w * sc);
  *(ushort4*)(Wb + idx) = o;
}

// ============ kernel 2: QKV projection GEMM (M=16384, N=384, K=1024) ========
// 256 blocks x 512 threads (8 waves). Block = 64 rows x all 384 cols.
// Wave wv owns n-tiles wv*3..wv*3+2 over 4 m-tiles. x staged via LDS (shared
// by all waves, fp32->bf16 once); W B-frags read directly from global
// (L2-resident 768KB, each frag is a contiguous 16B b128 load).
__global__ __launch_bounds__(512, 2) void proj_k(const float* __restrict__ x,
    const float* __restrict__ bq, const float* __restrict__ bk,
    const float* __restrict__ bv, const unsigned short* __restrict__ Wb,
    unsigned short* __restrict__ Qg, unsigned short* __restrict__ Kg,
    unsigned short* __restrict__ Vtg) {
  __shared__ unsigned short smem[128 * 72];  // 18.4KB: xs[64][136] or vt[128][72]
  unsigned short* xs = smem;
  const int tid = threadIdx.x;
  const int wv = tid >> 6, ln = tid & 15, quad = (tid >> 4) & 3;
  const int mt = blockIdx.x;

  float bias[3];
  int tensor_[3], hcol_[3];
#pragma unroll
  for (int nt = 0; nt < 3; nt++) {
    int g_nt = wv * 3 + nt;
    int tensor = g_nt >> 3;
    int hcol = ((g_nt & 7) << 4) + ln;
    tensor_[nt] = tensor; hcol_[nt] = hcol;
    bias[nt] = (tensor == 0) ? bq[hcol] * QSCALE : (tensor == 1 ? bk[hcol] : bv[hcol]);
  }

  f32x4 acc[4][3];
  f32x4 zero = {0.f, 0.f, 0.f, 0.f};
#pragma unroll
  for (int m = 0; m < 4; m++)
#pragma unroll
    for (int nt = 0; nt < 3; nt++) acc[m][nt] = zero;

  float4 rX[4];  // 2 granules/thread staged in regs (double-buffer)
#define LOAD_X(KC)                                                             \
  _Pragma("unroll") for (int k = 0; k < 2; k++) {                              \
    int g = k * 512 + tid; int row = g >> 4, gc = g & 15;                      \
    const float* p = x + (size_t)(mt * 64 + row) * 1024 + (KC) * 128 + gc * 8; \
    rX[k * 2]     = *(const float4*)p;                                         \
    rX[k * 2 + 1] = *(const float4*)(p + 4);                                   \
  }
#define WRITE_X()                                                              \
  _Pragma("unroll") for (int k = 0; k < 2; k++) {                              \
    int g = k * 512 + tid; int row = g >> 4, gc = g & 15;                      \
    float4 f0 = rX[k * 2], f1 = rX[k * 2 + 1];                                 \
    u32x4 u;                                                                   \
    u.x = f2bf(f0.x) | ((unsigned)f2bf(f0.y) << 16);                           \
    u.y = f2bf(f0.z) | ((unsigned)f2bf(f0.w) << 16);                           \
    u.z = f2bf(f1.x) | ((unsigned)f2bf(f1.y) << 16);                           \
    u.w = f2bf(f1.z) | ((unsigned)f2bf(f1.w) << 16);                           \
    *(u32x4*)&xs[row * 136 + gc * 8] = u;                                      \
  }

  LOAD_X(0);
  for (int kc = 0; kc < 8; kc++) {
    WRITE_X();
    __syncthreads();
    if (kc < 7) { LOAD_X(kc + 1); }
#pragma unroll
    for (int kk2 = 0; kk2 < 4; kk2++) {
      s16x8 a[4];
#pragma unroll
      for (int m = 0; m < 4; m++)
        a[m] = __builtin_bit_cast(s16x8,
            *(const u32x4*)&xs[(m * 16 + ln) * 136 + kk2 * 32 + quad * 8]);
#pragma unroll
      for (int nt = 0; nt < 3; nt++) {
        int nrow = (wv * 3 + nt) * 16 + ln;
        s16x8 b = __builtin_bit_cast(s16x8,
            *(const u32x4*)(Wb + (size_t)nrow * 1024 + kc * 128 + kk2 * 32 + quad * 8));
#pragma unroll
        for (int m = 0; m < 4; m++)
          acc[m][nt] = mfma16(a[m], b, acc[m][nt]);
      }
    }
    __syncthreads();
  }

  // epilogue: C-layout row = quad*4+reg, col = ln (m89-verified)
  const int r0 = mt * 64;
  const int batch = r0 >> 12, t0 = r0 & 4095;
  unsigned short* vt = smem;  // reuse as Vt tile [128 h][64 t + pad 8]
#pragma unroll
  for (int nt = 0; nt < 3; nt++) {
#pragma unroll
    for (int m = 0; m < 4; m++) {
#pragma unroll
      for (int reg = 0; reg < 4; reg++) {
        float val = acc[m][nt][reg] + bias[nt];
        unsigned short h = f2bf(val);
        int rl = m * 16 + quad * 4 + reg;
        if (tensor_[nt] == 0)      Qg[(size_t)(r0 + rl) * 128 + hcol_[nt]] = h;
        else if (tensor_[nt] == 1) Kg[(size_t)(r0 + rl) * 128 + hcol_[nt]] = h;
        else                       vt[hcol_[nt] * 72 + rl] = h;   // transpose in LDS
      }
    }
  }
  __syncthreads();
  // coalesced copy-out: vt [128 h][64 t] -> Vtg[b][h][t]
#pragma unroll
  for (int k = 0; k < 2; k++) {
    int g = k * 512 + tid;
    int h = g >> 3, gc = g & 7;
    u32x4 u = *(const u32x4*)&vt[h * 72 + gc * 8];
    *(u32x4*)((char*)Vtg + (size_t)batch * 1048576 + (size_t)h * 8192 + t0 * 2 + gc * 16) = u;
  }
}

// ============ kernel 3: causal flash attention, K-split ============
// BM=64 (4 waves x 16 q-rows, Q in regs), BN=64 chunks, 16 chunks/segment
// (1024 keys). Grid 1024 = 4b x 64qt x 4seg; invalid segs exit. Each block
// writes unnormalized partial (o, m, l); combine_k merges. Register-staged
// double-buffered K/V.
__global__ __launch_bounds__(256, 3) void attn_k(const unsigned short* __restrict__ Qg,
    const unsigned short* __restrict__ Kg, const unsigned short* __restrict__ Vtg,
    float* __restrict__ Po, float* __restrict__ Pm, float* __restrict__ Plr) {
  __shared__ unsigned short Kl[64 * 136];  // 17.4KB
  __shared__ unsigned short Vl[128 * 72];  // 18.4KB
  __shared__ unsigned short Pl[64 * 72];   //  9.2KB  (total 45KB -> 3 blocks/CU)
  const int tid = threadIdx.x;
  const int wv = tid >> 6, ln = tid & 15, quad = (tid >> 4) & 3;
  const int id = blockIdx.x;
  const int seg = id & 3, qt = (id >> 2) & 63, b = id >> 8;
  if (seg * 16 > qt) return;          // segment beyond causal range
  const int qbase = qt * 64;
  const int nch = min(16, qt + 1 - seg * 16);

  const char* Kbase = (const char*)Kg + (size_t)b * 1048576;  // [t][h] 256B rows
  const char* Vbase = (const char*)Vtg + (size_t)b * 1048576; // [h][t] 8192B rows

  // Q fragments: A-layout (m=ln, k=quad*8+j + 32*ks)
  const int qrow = b * 4096 + qbase + wv * 16 + ln;
  u32x4 qf[4];
#pragma unroll
  for (int ks = 0; ks < 4; ks++)
    qf[ks] = *(const u32x4*)((const char*)Qg + (size_t)qrow * 256 + ks * 64 + quad * 16);

  f32x4 o[8];
  f32x4 zero = {0.f, 0.f, 0.f, 0.f};
#pragma unroll
  for (int i = 0; i < 8; i++) o[i] = zero;
  float m_run[4] = {-1e30f, -1e30f, -1e30f, -1e30f};
  float l_run[4] = {0.f, 0.f, 0.f, 0.f};

  u32x4 rK[4], rV[4];
#define LOAD_KV(T0)                                                            \
  _Pragma("unroll") for (int k = 0; k < 4; k++) {                              \
    int g = k * 256 + tid;                                                     \
    rK[k] = *(const u32x4*)(Kbase + (size_t)(T0) * 256 + (size_t)g * 16);      \
  }                                                                            \
  _Pragma("unroll") for (int k = 0; k < 4; k++) {                              \
    int g = k * 256 + tid; int row = g >> 3, gc = g & 7;                       \
    rV[k] = *(const u32x4*)(Vbase + (size_t)row * 8192 + (T0) * 2 + gc * 16);  \
  }
#define WRITE_KV()                                                             \
  _Pragma("unroll") for (int k = 0; k < 4; k++) {                              \
    int g = k * 256 + tid; int row = g >> 4, gc = g & 15;                      \
    *(u32x4*)&Kl[row * 136 + gc * 8] = rK[k];                                  \
  }                                                                            \
  _Pragma("unroll") for (int k = 0; k < 4; k++) {                              \
    int g = k * 256 + tid; int row = g >> 3, gc = g & 7;                       \
    *(u32x4*)&Vl[row * 72 + gc * 8] = rV[k];                                   \
  }

  LOAD_KV(seg * 1024);
  for (int ci = 0; ci < nch; ci++) {
    const int c_glob = seg * 16 + ci;
    const int t0 = c_glob * 64;
    WRITE_KV();
    __syncthreads();
    if (ci + 1 < nch) { LOAD_KV(t0 + 64); }

    // S = Q K^T (log2 domain via QSCALE folding)
    f32x4 s[4];
#pragma unroll
    for (int nt = 0; nt < 4; nt++) {
      s[nt] = zero;
#pragma unroll
      for (int ks = 0; ks < 4; ks++) {
        s16x8 bb = __builtin_bit_cast(s16x8,
            *(const u32x4*)&Kl[(nt * 16 + ln) * 136 + ks * 32 + quad * 8]);
        s[nt] = mfma16(__builtin_bit_cast(s16x8, qf[ks]), bb, s[nt]);
      }
    }
    // causal mask: only the diagonal chunk
    if (c_glob == qt) {
#pragma unroll
      for (int nt = 0; nt < 4; nt++)
#pragma unroll
        for (int reg = 0; reg < 4; reg++) {
          int kidx = t0 + nt * 16 + ln;
          int qidx = qbase + wv * 16 + quad * 4 + reg;
          if (kidx > qidx) s[nt][reg] = -1e30f;
        }
    }
    // online softmax; rows owned per 16-lane group (row = quad*4+reg)
    float mx[4], al[4], rs[4];
#pragma unroll
    for (int reg = 0; reg < 4; reg++)
      mx[reg] = fmaxf(fmaxf(s[0][reg], s[1][reg]), fmaxf(s[2][reg], s[3][reg]));
#pragma unroll
    for (int off = 1; off < 16; off <<= 1)
#pragma unroll
      for (int reg = 0; reg < 4; reg++)
        mx[reg] = fmaxf(mx[reg], __shfl_xor(mx[reg], off, 64));
#pragma unroll
    for (int reg = 0; reg < 4; reg++) {
      float mn = fmaxf(m_run[reg], mx[reg]);
      al[reg] = __builtin_amdgcn_exp2f(m_run[reg] - mn);
      m_run[reg] = mn;
      rs[reg] = 0.f;
    }
#pragma unroll
    for (int nt = 0; nt < 4; nt++)
#pragma unroll
      for (int reg = 0; reg < 4; reg++) {
        float pv = __builtin_amdgcn_exp2f(s[nt][reg] - m_run[reg]);
        s[nt][reg] = pv;
        rs[reg] += pv;
      }
#pragma unroll
    for (int off = 1; off < 16; off <<= 1)
#pragma unroll
      for (int reg = 0; reg < 4; reg++)
        rs[reg] += __shfl_xor(rs[reg], off, 64);
#pragma unroll
    for (int reg = 0; reg < 4; reg++)
      l_run[reg] = l_run[reg] * al[reg] + rs[reg];
#pragma unroll
    for (int i = 0; i < 8; i++)
#pragma unroll
      for (int reg = 0; reg < 4; reg++)
        o[i][reg] *= al[reg];

    // P: C-layout -> LDS -> A-layout (wave-private rows)
#pragma unroll
    for (int nt = 0; nt < 4; nt++)
#pragma unroll
      for (int reg = 0; reg < 4; reg++)
        Pl[(wv * 16 + quad * 4 + reg) * 72 + nt * 16 + ln] = f2bf(s[nt][reg]);

#pragma unroll
    for (int ks2 = 0; ks2 < 2; ks2++) {
      s16x8 pa = __builtin_bit_cast(s16x8,
          *(const u32x4*)&Pl[(wv * 16 + ln) * 72 + ks2 * 32 + quad * 8]);
#pragma unroll
      for (int nh = 0; nh < 8; nh++) {
        s16x8 vb = __builtin_bit_cast(s16x8,
            *(const u32x4*)&Vl[(nh * 16 + ln) * 72 + ks2 * 32 + quad * 8]);
        o[nh] = mfma16(pa, vb, o[nh]);
      }
    }
    __syncthreads();
  }

  // epilogue: write unnormalized partial + m,l
  float* po = Po + (size_t)id * 8192;
#pragma unroll
  for (int reg = 0; reg < 4; reg++) {
    int row = wv * 16 + quad * 4 + reg;
#pragma unroll
    for (int nh = 0; nh < 8; nh++)
      po[row * 128 + nh * 16 + ln] = o[nh][reg];
    if (ln == 0) {
      Pm[id * 64 + row] = m_run[reg];
      Plr[id * 64 + row] = l_run[reg];
    }
  }
}

// ============ kernel 4: combine partials ============
// 256 blocks (b,qt) x 256 threads; thread = 1 row x 32 cols.
__global__ __launch_bounds__(256) void combine_k(const float* __restrict__ Po,
    const float* __restrict__ Pm, const float* __restrict__ Plr,
    float* __restrict__ out) {
  const int id = blockIdx.x;       // 0..255
  const int b = id >> 6, qt = id & 63;
  const int nseg = (qt >> 4) + 1;
  const int tid = threadIdx.x;
  const int row = tid >> 2;
  const int cq = (tid & 3) * 32;
  const int slot0 = id * 4;

  float M = -1e30f;
  for (int s = 0; s < nseg; s++)
    M = fmaxf(M, Pm[(slot0 + s) * 64 + row]);
  float L = 0.f;
  f32x4 acc[8];
  f32x4 zero = {0.f, 0.f, 0.f, 0.f};
#pragma unroll
  for (int i = 0; i < 8; i++) acc[i] = zero;
  for (int s = 0; s < nseg; s++) {
    float w = __builtin_amdgcn_exp2f(Pm[(slot0 + s) * 64 + row] - M);
    L += w * Plr[(slot0 + s) * 64 + row];
    const float* p = Po + (size_t)(slot0 + s) * 8192 + row * 128 + cq;
#pragma unroll
    for (int i = 0; i < 8; i++) {
      f32x4 v = *(const f32x4*)(p + i * 4);
      acc[i] += w * v;
    }
  }
  float inv = 1.f / L;
  float* op = out + (size_t)(b * 4096 + qt * 64 + row) * 128 + cq;
#pragma unroll
  for (int i = 0; i < 8; i++)
    *(f32x4*)(op + i * 4) = acc[i] * inv;
}

// ============ launch ============
extern "C" void kernel_launch(void* const* d_in, const int* in_sizes, int n_in,
                              void* d_out, int out_size, void* d_ws, size_t ws_size,
                              hipStream_t stream) {
  const float* x  = (const float*)d_in[0];
  const float* Wq = (const float*)d_in[1];
  const float* bq = (const float*)d_in[2];
  const float* Wk = (const float*)d_in[3];
  const float* bk = (const float*)d_in[4];
  const float* Wv = (const float*)d_in[5];
  const float* bv = (const float*)d_in[6];
  float* out = (float*)d_out;

  char* wsb = (char*)d_ws;
  unsigned short* Wb  = (unsigned short*)wsb;                 // 786432 B
  unsigned short* Qg  = (unsigned short*)(wsb + 786432);      // 4 MB
  unsigned short* Kg  = (unsigned short*)(wsb + 4980736);     // 4 MB
  unsigned short* Vtg = (unsigned short*)(wsb + 9175040);     // 4 MB
  float* Po  = (float*)(wsb + 13369344);                      // 32 MB
  float* Pm  = (float*)(wsb + 46923776);                      // 256 KB
  float* Plr = (float*)(wsb + 47185920);                      // 256 KB

  wconv_k<<<dim3(384), dim3(256), 0, stream>>>(Wq, Wk, Wv, Wb);
  proj_k<<<dim3(256), dim3(512), 0, stream>>>(x, bq, bk, bv, Wb, Qg, Kg, Vtg);
  attn_k<<<dim3(1024), dim3(256), 0, stream>>>(Qg, Kg, Vtg, Po, Pm, Plr);
  combine_k<<<dim3(256), dim3(256), 0, stream>>>(Po, Pm, Plr, out);
}